// Round 1
// baseline (929.129 us; speedup 1.0000x reference)
//
#include <hip/hip_runtime.h>

// ChannelGroupConv: 1x1 grouped-causal conv == block-triangular 128x128 GEMM
// over 4*512*512 pixels. Memory-bound (1.07 GB traffic). bf16 MFMA so compute
// is negligible; weights live in VGPR fragments for the whole kernel.

#define HW        (512 * 512)          // 2^18
#define NPIX_TILE 64                   // pixels per block tile
#define NTILES    (4 * HW / NPIX_TILE) // 16384

typedef __attribute__((ext_vector_type(8))) short bf16x8;  // 8 bf16 = 4 VGPRs
typedef __attribute__((ext_vector_type(4))) float f32x4;

__device__ inline unsigned short f2bf_rne(float f) {
    unsigned u = __float_as_uint(f);
    u += 0x7FFFu + ((u >> 16) & 1u);   // round-to-nearest-even
    return (unsigned short)(u >> 16);
}

__global__ __launch_bounds__(256, 2)
void cgc_mfma_kernel(const float* __restrict__ x, const float* __restrict__ w,
                     const float* __restrict__ bias, float* __restrict__ out,
                     int ntiles) {
    const int tid  = threadIdx.x;
    const int lane = tid & 63;
    const int wv   = tid >> 6;     // wave 0..3 -> 16-pixel slice of the tile
    const int quad = lane >> 4;    // 0..3
    const int l16  = lane & 15;

    // ---- A fragments: masked weight, bf16, held in VGPRs for all tiles ----
    // afrag[t][kk]: lane holds A[co=16t+l16][ci=32kk+quad*8+j], j=0..7.
    // Mask: co uses ci < (co & ~7) + 8. k0 is 8-aligned and the limit is a
    // multiple of 8, so each lane's 8-elem group is wholly kept or zeroed.
    bf16x8 afrag[8][4];
    #pragma unroll
    for (int t = 0; t < 8; ++t) {
        const int co   = 16 * t + l16;
        const int klim = (co & ~7) + 8;
        #pragma unroll
        for (int kk = 0; kk <= t / 2; ++kk) {      // triangular kk-skip: 20 frags
            const int k0 = 32 * kk + quad * 8;
            const float* wp = w + co * 128 + k0;
            bf16x8 f;
            #pragma unroll
            for (int j = 0; j < 8; ++j) {
                float v = (k0 < klim) ? wp[j] : 0.0f;
                f[j] = (short)f2bf_rne(v);
            }
            afrag[t][kk] = f;
        }
    }

    // ---- bias preload, in C/D layout: D[row=quad*4+r][col=l16], co=16t+row
    f32x4 biasr[8];
    #pragma unroll
    for (int t = 0; t < 8; ++t)
        #pragma unroll
        for (int r = 0; r < 4; ++r)
            biasr[t][r] = bias[16 * t + quad * 4 + r];

    // ---- grid-stride over 64-pixel tiles ----
    for (int tile = blockIdx.x; tile < ntiles; tile += gridDim.x) {
        const int b = tile >> 12;                       // tile / (HW/64)
        const int p = ((tile & 4095) << 6) + (wv << 4) + l16;  // this lane's pixel
        const size_t base = ((size_t)b << 25) + (size_t)p;     // b*128*HW + p

        // load raw fp32 x: fv[kk][j] = x[b][32kk+quad*8+j][p]
        const float* xp = x + base + ((size_t)(quad * 8) << 18);
        float fv[4][8];
        #pragma unroll
        for (int kk = 0; kk < 4; ++kk)
            #pragma unroll
            for (int j = 0; j < 8; ++j)
                fv[kk][j] = xp[(size_t)(kk * 32 + j) << 18];

        // convert to bf16 B fragments: B[ci][pix], lane: pix=l16, k=quad*8+j
        bf16x8 bfrag[4];
        #pragma unroll
        for (int kk = 0; kk < 4; ++kk) {
            bf16x8 f;
            #pragma unroll
            for (int j = 0; j < 8; ++j) f[j] = (short)f2bf_rne(fv[kk][j]);
            bfrag[kk] = f;
        }

        // accumulate: init with bias, 20 MFMAs (triangular skip)
        f32x4 acc[8];
        #pragma unroll
        for (int t = 0; t < 8; ++t) acc[t] = biasr[t];
        #pragma unroll
        for (int kk = 0; kk < 4; ++kk)
            #pragma unroll
            for (int t = 2 * kk; t < 8; ++t)
                acc[t] = __builtin_amdgcn_mfma_f32_16x16x32_bf16(
                    afrag[t][kk], bfrag[kk], acc[t], 0, 0, 0);

        // store: lane holds D[co=16t+quad*4+r][pix=p]
        float* op = out + base + ((size_t)(quad * 4) << 18);
        #pragma unroll
        for (int t = 0; t < 8; ++t)
            #pragma unroll
            for (int r = 0; r < 4; ++r)
                op[(size_t)(16 * t + r) << 18] = acc[t][r];
    }
}

extern "C" void kernel_launch(void* const* d_in, const int* in_sizes, int n_in,
                              void* d_out, int out_size, void* d_ws, size_t ws_size,
                              hipStream_t stream) {
    const float* x    = (const float*)d_in[0];
    const float* w    = (const float*)d_in[1];
    const float* bias = (const float*)d_in[2];
    float* out        = (float*)d_out;

    dim3 grid(2048), block(256);
    hipLaunchKernelGGL(cgc_mfma_kernel, grid, block, 0, stream,
                       x, w, bias, out, NTILES);
}